// Round 1
// 128.265 us; speedup vs baseline: 1.0413x; 1.0413x over previous
//
#include <hip/hip_runtime.h>

// GNN layer: out = segment_sum(nf[src], dst) @ W.T + b
// N=50000, E=800000, D=128.
// R14: overhead attack (kernel was latency/overhead-bound: HBM 25%, VALU 33%,
// MFMA 1%).
//  1) Phase B: per-QUARTER node ownership. Each 16-lane quarter walks exactly
//     its node's edge list (2-edge ILP, masked tail) -> no more ceil-16
//     clamped gathers (~47% of VMEM issue was duplicates), no shfl butterfly,
//     all 64 lanes pack+store 4 tile rows at once. float2 accumulators for
//     v_pk_add_f32.
//  2) All block scans -> wave shfl scans (A1: 16 barriers -> 1, A3: 14 -> 2,
//     producer 391-scan: 18 -> 2).
//  3) offs transposed to bucket-major: consumer A1 reads 2 coalesced rows
//     instead of 196 scattered lines.
//  4) pk held in registers across the node scan (pkbuf LDS pass removed).
// Rest (bucketing producer, MFMA Phase C) = R13.

constexpr int NN = 50000;
constexpr int NE = 800000;
constexpr int D  = 128;

constexpr int BS   = 128;                      // nodes per bucket
constexpr int NB   = (NN + BS - 1) / BS;       // 391 buckets
constexpr int EPB  = 4096;                     // edges per producer block
constexpr int NSB  = (NE + EPB - 1) / EPB;     // 196 producer blocks
constexpr int CAP  = 4096;                     // per-bucket edge cap

constexpr int AROWU = 136;                     // tile row stride (ushorts)

typedef __attribute__((ext_vector_type(8))) short bf16x8;
typedef __attribute__((ext_vector_type(4))) float f32x4;
typedef __attribute__((ext_vector_type(2))) float f32x2;

__device__ inline unsigned short f2bf(float f) {           // RNE
    unsigned u = __float_as_uint(f);
    return (unsigned short)((u + 0x7fffu + ((u >> 16) & 1u)) >> 16);
}
__device__ inline float bflo(unsigned v) { return __uint_as_float(v << 16); }
__device__ inline float bfhi(unsigned v) { return __uint_as_float(v & 0xffff0000u); }

__device__ inline int wscan(int v) {           // wave-inclusive scan (64)
    #pragma unroll
    for (int o = 1; o < 64; o <<= 1) {
        int u = __shfl_up(v, o);
        if ((int)(threadIdx.x & 63) >= o) v += u;
    }
    return v;
}

__device__ inline void acc8(f32x2& a0, f32x2& a1, f32x2& a2, f32x2& a3, uint4 v) {
    a0 += (f32x2){bflo(v.x), bfhi(v.x)};
    a1 += (f32x2){bflo(v.y), bfhi(v.y)};
    a2 += (f32x2){bflo(v.z), bfhi(v.z)};
    a3 += (f32x2){bflo(v.w), bfhi(v.w)};
}

// ---- 1. fused prep (bf16 cvt) + bucket-sort partition ---------------------
constexpr int NF4 = NN * D / 4;                           // 1,600,000
constexpr int W4  = D * D / 4;                            // 4,096
constexpr int NBLK_P = (NF4 + W4 + 511) / 512;            // 3134
constexpr int GRID_A = NSB + NBLK_P;

__global__ __launch_bounds__(512) void k_prep_bucket(
    const float* __restrict__ nf, const float* __restrict__ W,
    const int* __restrict__ ei,
    ushort* __restrict__ nfh, ushort* __restrict__ Wh,
    ushort* __restrict__ offs, unsigned* __restrict__ buf)
{
    __shared__ int hist[NB], cur[NB];              // 3128 B
    __shared__ int wsum[8];
    __shared__ unsigned spk[EPB];                  // 16384 B
    const int t = threadIdx.x, lane = t & 63, w = t >> 6;

    if (blockIdx.x < NSB) {
        const int blk = blockIdx.x;
        const int e0  = blk * EPB;
        int cnt = NE - e0; if (cnt > EPB) cnt = EPB;

        for (int i = t; i < NB; i += 512) hist[i] = 0;
        __syncthreads();

        unsigned pk[8];
        #pragma unroll
        for (int j = 0; j < 8; ++j) {
            int idx = j * 512 + t;
            if (idx < cnt) {
                int e = e0 + idx;
                unsigned s = (unsigned)ei[e];
                unsigned d = (unsigned)ei[NE + e];
                pk[j] = (d << 16) | s;             // bucket = pk >> 23
                atomicAdd(&hist[pk[j] >> 23], 1);
            }
        }
        __syncthreads();
        // wave shfl scan over 391 (waves 0..6 carry data, wave 7 zeros)
        int h = (t < NB) ? hist[t] : 0;
        int v = wscan(h);
        if (lane == 63) wsum[w] = v;
        __syncthreads();
        int addv = 0;
        #pragma unroll
        for (int i = 0; i < 8; ++i) addv += (i < w) ? wsum[i] : 0;
        v += addv;
        if (t < NB) {
            int ex = v - h;                        // exclusive base
            cur[t] = ex;
            offs[t * NSB + blk] = (ushort)ex;      // TRANSPOSED: bucket-major
        }
        if (t == 0) offs[NB * NSB + blk] = (ushort)cnt;
        __syncthreads();
        #pragma unroll
        for (int j = 0; j < 8; ++j) {
            int idx = j * 512 + t;
            if (idx < cnt) {
                int l = atomicAdd(&cur[pk[j] >> 23], 1);
                spk[l] = pk[j];
            }
        }
        __syncthreads();
        for (int i = t; i < cnt; i += 512)         // dense coalesced 16KB
            buf[(size_t)blk * EPB + i] = spk[i];
    } else {
        // prep branch: bf16 conversion
        int i = (blockIdx.x - NSB) * 512 + t;
        if (i < NF4) {
            float4 v = ((const float4*)nf)[i];
            ((ushort4*)nfh)[i] = make_ushort4(f2bf(v.x), f2bf(v.y), f2bf(v.z), f2bf(v.w));
        } else if (i < NF4 + W4) {
            int k = i - NF4;
            float4 v = ((const float4*)W)[k];
            ((ushort4*)Wh)[k] = make_ushort4(f2bf(v.x), f2bf(v.y), f2bf(v.z), f2bf(v.w));
        }
    }
}

// ---- 2. fused gather-sort + aggregate + linear ----------------------------
__global__ __launch_bounds__(1024, 8) void k_sort_agg(
    const unsigned* __restrict__ nfh, const unsigned* __restrict__ buf,
    const ushort* __restrict__ offs, const ushort* __restrict__ Wh,
    const float* __restrict__ bias, float* __restrict__ out)
{
    __shared__ ushort srt[CAP];                     // 8192 B
    __shared__ int scnt[256];                       // 1024 B
    __shared__ int sbase[NSB], rbase[NSB];          // 1568 B
    __shared__ int hist[BS], off[BS], cur[BS];      // 1536 B
    __shared__ int wred[16];
    __shared__ __align__(16) unsigned tile[BS * AROWU / 2];  // 34816 B (~47.5KB)
    const int b = blockIdx.x, t = threadIdx.x;
    const int lane = t & 63, w = t >> 6;

    // --- Phase A1: per-producer run bases/counts -> wave shfl scan (1 barrier)
    int my = 0;
    if (t < NSB) {
        int o0 = (int)offs[b * NSB + t];           // coalesced 392B row
        int o1 = (int)offs[(b + 1) * NSB + t];
        rbase[t] = o0;
        my = o1 - o0;
    }
    if (t < BS) hist[t] = 0;
    int vs = 0;
    if (w < 4) {
        vs = wscan(my);
        if (lane == 63) wred[w] = vs;
    }
    __syncthreads();
    if (w < 4) {
        int addv = 0;
        #pragma unroll
        for (int i = 0; i < 3; ++i) addv += (i < w) ? wred[i] : 0;
        vs += addv;
        scnt[t] = vs;                              // global inclusive
        if (t < NSB) sbase[t] = vs - my;
    }
    __syncthreads();
    int total = scnt[NSB - 1];
    if (total > CAP) total = CAP;                  // defensive

    // --- Phase A2: load pk into REGISTERS + node histogram (no pkbuf)
    unsigned mypk[4];
    int mycnt = 0;
    #pragma unroll
    for (int j = 0; j < 4; ++j) {
        int p = t + j * 1024;
        if (p < total) {
            int lo = 0, hi = NSB - 1;              // min i: scnt[i] > p
            while (lo < hi) {
                int mid = (lo + hi) >> 1;
                if (scnt[mid] > p) hi = mid; else lo = mid + 1;
            }
            unsigned pk = buf[(size_t)lo * EPB + rbase[lo] + (p - sbase[lo])];
            mypk[j] = pk;
            atomicAdd(&hist[(pk >> 16) & (BS - 1)], 1);
            mycnt = j + 1;
        }
    }
    __syncthreads();

    // --- Phase A3: node wave-scan (2 barriers) + scatter into srt (local CSR)
    int hv = (t < BS) ? hist[t] : 0;
    int nv = 0;
    if (w < 2) {
        nv = wscan(hv);
        if (lane == 63) wred[8 + w] = nv;
    }
    __syncthreads();
    if (t < BS) {
        int ex = nv + ((w == 1) ? wred[8] : 0) - hv;
        off[t] = ex; cur[t] = ex;
    }
    __syncthreads();
    #pragma unroll
    for (int j = 0; j < 4; ++j) {
        if (j < mycnt) {
            unsigned pk = mypk[j];
            int n = (pk >> 16) & (BS - 1);
            int p = atomicAdd(&cur[n], 1);
            srt[p] = (ushort)(pk & 0xffffu);
        }
    }
    __syncthreads();

    // --- Phase B: per-quarter node ownership, exact edge walk
    // quarter qq owns node n = w*8 + i*4 + qq; 16 lanes x uint4 = full row.
    const int qq = lane >> 4;
    const int sl = lane & 15;
    const uint4* nfv = (const uint4*)nfh;          // row = idx*16 uint4s

    #pragma unroll 1
    for (int i = 0; i < 2; ++i) {
        const int n = w * 8 + i * 4 + qq;
        const int beg = off[n], cnt = hist[n];
        f32x2 a0 = {0.f, 0.f}, a1 = {0.f, 0.f}, a2 = {0.f, 0.f}, a3 = {0.f, 0.f};
        int p = 0;
        for (; p + 2 <= cnt; p += 2) {             // 2 gathers in flight
            const int s0 = srt[beg + p];
            const int s1 = srt[beg + p + 1];
            const uint4 v0 = nfv[(size_t)s0 * 16 + sl];
            const uint4 v1 = nfv[(size_t)s1 * 16 + sl];
            acc8(a0, a1, a2, a3, v0);
            acc8(a0, a1, a2, a3, v1);
        }
        if (p < cnt) {                             // odd tail (masked)
            const int s0 = srt[beg + p];
            const uint4 v0 = nfv[(size_t)s0 * 16 + sl];
            acc8(a0, a1, a2, a3, v0);
        }
        uint4 o;                                   // all 64 lanes: 4 rows/wave
        o.x = (unsigned)f2bf(a0.x) | ((unsigned)f2bf(a0.y) << 16);
        o.y = (unsigned)f2bf(a1.x) | ((unsigned)f2bf(a1.y) << 16);
        o.z = (unsigned)f2bf(a2.x) | ((unsigned)f2bf(a2.y) << 16);
        o.w = (unsigned)f2bf(a3.x) | ((unsigned)f2bf(a3.y) << 16);
        *(uint4*)(tile + n * (AROWU / 2) + sl * 4) = o;
    }
    __syncthreads();

    // --- Phase C: 8 tiles x 8 col-chunks = 64 MFMA tasks over 16 waves
    const int m = lane & 15, q = lane >> 4;
    const ushort* lds = (const ushort*)tile;
    #pragma unroll
    for (int i = 0; i < 4; ++i) {
        const int task = w + 16 * i;                // 0..63, bijective
        const int t16  = task >> 3;                 // row-tile 0..7
        const int c0   = (task & 7) * 16;           // col chunk
        const int grow0 = b * BS + t16 * 16;
        if (grow0 < NN) {                           // last bucket: 5 full tiles
            bf16x8 a[4];
            const ushort* arow = lds + (t16 * 16 + m) * AROWU + q * 8;
            #pragma unroll
            for (int kk = 0; kk < 4; ++kk)
                a[kk] = *(const bf16x8*)(arow + kk * 32);
            float bv = bias[c0 + m];
            f32x4 acc = { bv, bv, bv, bv };
            const ushort* wrow = Wh + (size_t)(c0 + m) * D + q * 8;
            #pragma unroll
            for (int kk = 0; kk < 4; ++kk) {
                bf16x8 bb = *(const bf16x8*)(wrow + kk * 32);
                acc = __builtin_amdgcn_mfma_f32_16x16x32_bf16(a[kk], bb, acc, 0, 0, 0);
            }
            float* op = out + (size_t)(grow0 + q * 4) * D + c0 + m;
            op[0]     = acc[0];
            op[D]     = acc[1];
            op[2 * D] = acc[2];
            op[3 * D] = acc[3];
        }
    }
}

extern "C" void kernel_launch(void* const* d_in, const int* in_sizes, int n_in,
                              void* d_out, int out_size, void* d_ws, size_t ws_size,
                              hipStream_t stream) {
    const float* nf = (const float*)d_in[0];
    const int*   ei = (const int*)d_in[1];
    const float* W  = (const float*)d_in[2];
    const float* b  = (const float*)d_in[3];
    float* out = (float*)d_out;

    // workspace (~16.2 MB)
    ushort*   nfh  = (ushort*)d_ws;                    // NN*D bf16 = 12.8 MB
    ushort*   Wh   = nfh + (size_t)NN * D;             // 32 KB
    unsigned* buf  = (unsigned*)(Wh + D * D);          // NSB*EPB u32 = 3.2 MB
    ushort*   offs = (ushort*)(buf + (size_t)NSB * EPB); // (NB+1)*NSB = 154 KB

    k_prep_bucket<<<GRID_A, 512, 0, stream>>>(nf, W, ei, nfh, Wh, offs, buf);
    k_sort_agg   <<<NB, 1024, 0, stream>>>((const unsigned*)nfh, buf, offs, Wh, b, out);
}